// Round 1
// baseline (817.935 us; speedup 1.0000x reference)
//
#include <hip/hip_runtime.h>

#define HD 100   // hidden width
#define DD 6     // state dim
#define TT 8     // timesteps in input_seq
#define NSTEP 8  // fixed RK4 steps over [0,1]

struct SW {
    float W1[HD][DD];   // W1[h][d]
    float W2T[HD][DD];  // W2T[h][d] = W2[d][h]
    float b1[HD];
    float b2[DD];
    float Wl[DD];
    float bl;
};

__device__ __forceinline__ float fast_tanh(float x) {
    // tanh(x) = 1 - 2/(e^{2x}+1); e^{2x} = exp2(x * 2*log2(e))
    float e = __builtin_amdgcn_exp2f(x * 2.885390081777927f);
    return 1.0f - 2.0f * __builtin_amdgcn_rcpf(e + 1.0f);
}

__device__ __forceinline__ void feval(const SW& s, const float (&yy)[DD], float (&k)[DD]) {
    #pragma unroll
    for (int d = 0; d < DD; ++d) k[d] = s.b2[d];
    #pragma unroll 10
    for (int h = 0; h < HD; ++h) {
        float pre = s.b1[h];
        #pragma unroll
        for (int d = 0; d < DD; ++d) pre = fmaf(yy[d], s.W1[h][d], pre);
        float t = fast_tanh(pre);
        #pragma unroll
        for (int d = 0; d < DD; ++d) k[d] = fmaf(t, s.W2T[h][d], k[d]);
    }
}

__global__ __launch_bounds__(256) void ODEModel_74732430950754_kernel(
    const float* __restrict__ inp, const float* __restrict__ W1,
    const float* __restrict__ b1, const float* __restrict__ W2,
    const float* __restrict__ b2, const float* __restrict__ Wl,
    const float* __restrict__ bl, float* __restrict__ out, int B)
{
    __shared__ SW s;
    const int tid = threadIdx.x;
    for (int i = tid; i < HD * DD; i += 256) s.W1[i / DD][i % DD] = W1[i];
    for (int i = tid; i < HD * DD; i += 256) {
        int h = i / DD, d = i % DD;
        s.W2T[h][d] = W2[d * HD + h];
    }
    for (int i = tid; i < HD; i += 256) s.b1[i] = b1[i];
    if (tid < DD) { s.b2[tid] = b2[tid]; s.Wl[tid] = Wl[tid]; }
    if (tid == 0) s.bl = bl[0];
    __syncthreads();

    const int idx = blockIdx.x * 256 + tid;
    if (idx >= B) return;

    // y0 = input_seq[idx, T-1, :]
    float y[DD];
    #pragma unroll
    for (int d = 0; d < DD; ++d)
        y[d] = inp[(size_t)idx * (TT * DD) + (TT - 1) * DD + d];

    const float hs = 1.0f / (float)NSTEP;
    float k1[DD], k2[DD], k3[DD], k4[DD], yt[DD];

    #pragma unroll 1
    for (int st = 0; st < NSTEP; ++st) {
        feval(s, y, k1);
        #pragma unroll
        for (int d = 0; d < DD; ++d) yt[d] = fmaf(0.5f * hs, k1[d], y[d]);
        feval(s, yt, k2);
        #pragma unroll
        for (int d = 0; d < DD; ++d) yt[d] = fmaf(0.5f * hs, k2[d], y[d]);
        feval(s, yt, k3);
        #pragma unroll
        for (int d = 0; d < DD; ++d) yt[d] = fmaf(hs, k3[d], y[d]);
        feval(s, yt, k4);
        #pragma unroll
        for (int d = 0; d < DD; ++d)
            y[d] = fmaf(hs * (1.0f / 6.0f),
                        k1[d] + 2.0f * (k2[d] + k3[d]) + k4[d], y[d]);
    }

    float o = s.bl;
    #pragma unroll
    for (int d = 0; d < DD; ++d) o = fmaf(y[d], s.Wl[d], o);
    out[idx] = o;
}

extern "C" void kernel_launch(void* const* d_in, const int* in_sizes, int n_in,
                              void* d_out, int out_size, void* d_ws, size_t ws_size,
                              hipStream_t stream) {
    const float* inp = (const float*)d_in[0];
    const float* W1  = (const float*)d_in[1];
    const float* b1  = (const float*)d_in[2];
    const float* W2  = (const float*)d_in[3];
    const float* b2  = (const float*)d_in[4];
    const float* Wl  = (const float*)d_in[5];
    const float* bl  = (const float*)d_in[6];
    float* out = (float*)d_out;

    const int B = in_sizes[0] / (TT * DD);
    const int blocks = (B + 255) / 256;
    hipLaunchKernelGGL(ODEModel_74732430950754_kernel, dim3(blocks), dim3(256), 0, stream,
                       inp, W1, b1, W2, b2, Wl, bl, out, B);
}

// Round 2
// 446.729 us; speedup vs baseline: 1.8309x; 1.8309x over previous
//
#include <hip/hip_runtime.h>

#define HD 100   // hidden width
#define DD 6     // state dim
#define TT 8     // timesteps
#define NSTEP 8  // fixed RK4 steps
#define WPS 16   // packed weight row stride (floats) = 64B

typedef float v2f  __attribute__((ext_vector_type(2)));
typedef float v16f __attribute__((ext_vector_type(16)));

__device__ __forceinline__ v2f splat2(float s) { v2f r; r.x = s; r.y = s; return r; }
__device__ __forceinline__ v2f fma2(v2f a, v2f b, v2f c) {
    return __builtin_elementwise_fma(a, b, c);
}

__device__ __forceinline__ v2f tanh2(v2f x) {
    const float c = 2.885390081777927f; // 2*log2(e)
    v2f e;
    e.x = __builtin_amdgcn_exp2f(x.x * c);
    e.y = __builtin_amdgcn_exp2f(x.y * c);
    v2f r;
    r.x = __builtin_amdgcn_rcpf(e.x + 1.0f);
    r.y = __builtin_amdgcn_rcpf(e.y + 1.0f);
    // tanh = 1 - 2/(e^{2x}+1)
    return fma2(splat2(-2.0f), r, splat2(1.0f));
}

// Pack per-h rows: [b1, W1 row (6), W2T row (6), pad(3)] -> 64B aligned rows in ws
__global__ void pack_weights_kernel(const float* __restrict__ W1,
                                    const float* __restrict__ b1,
                                    const float* __restrict__ W2,
                                    float* __restrict__ wp)
{
    int h = blockIdx.x * blockDim.x + threadIdx.x;
    if (h >= HD) return;
    float* row = wp + (size_t)h * WPS;
    row[0] = b1[h];
    #pragma unroll
    for (int d = 0; d < DD; ++d) row[1 + d] = W1[h * DD + d];
    #pragma unroll
    for (int d = 0; d < DD; ++d) row[7 + d] = W2[d * HD + h];
    row[13] = 0.0f; row[14] = 0.0f; row[15] = 0.0f;
}

__device__ __forceinline__ void feval(const float* __restrict__ wp,
                                      const float (&b2v)[DD],
                                      const v2f (&y)[DD], v2f (&k)[DD])
{
    #pragma unroll
    for (int d = 0; d < DD; ++d) k[d] = splat2(b2v[d]);
    #pragma unroll 4
    for (int h = 0; h < HD; ++h) {
        // one wave-uniform 64B load -> s_load_dwordx16 (scalar pipe)
        v16f w = *reinterpret_cast<const v16f*>(wp + (size_t)h * WPS);
        v2f pre = splat2(w[0]);
        #pragma unroll
        for (int d = 0; d < DD; ++d) pre = fma2(y[d], splat2(w[1 + d]), pre);
        v2f t = tanh2(pre);
        #pragma unroll
        for (int d = 0; d < DD; ++d) k[d] = fma2(t, splat2(w[7 + d]), k[d]);
    }
}

__global__ __launch_bounds__(256) void ODEModel_74732430950754_kernel(
    const float* __restrict__ inp, const float* __restrict__ wp,
    const float* __restrict__ b2, const float* __restrict__ Wl,
    const float* __restrict__ bl, float* __restrict__ out, int B2)
{
    const int i = blockIdx.x * 256 + threadIdx.x;
    if (i >= B2) return;

    float b2v[DD];
    #pragma unroll
    for (int d = 0; d < DD; ++d) b2v[d] = b2[d];

    // two samples per thread: 2i and 2i+1
    const size_t stride = TT * DD;
    const size_t base0 = (size_t)(2 * i) * stride + (TT - 1) * DD;
    v2f y[DD];
    #pragma unroll
    for (int d = 0; d < DD; ++d) {
        y[d].x = inp[base0 + d];
        y[d].y = inp[base0 + stride + d];
    }

    const float hs = 1.0f / (float)NSTEP;
    v2f k1[DD], k2[DD], k3[DD], k4[DD], yt[DD];

    #pragma unroll 1
    for (int st = 0; st < NSTEP; ++st) {
        feval(wp, b2v, y, k1);
        #pragma unroll
        for (int d = 0; d < DD; ++d) yt[d] = fma2(splat2(0.5f * hs), k1[d], y[d]);
        feval(wp, b2v, yt, k2);
        #pragma unroll
        for (int d = 0; d < DD; ++d) yt[d] = fma2(splat2(0.5f * hs), k2[d], y[d]);
        feval(wp, b2v, yt, k3);
        #pragma unroll
        for (int d = 0; d < DD; ++d) yt[d] = fma2(splat2(hs), k3[d], y[d]);
        feval(wp, b2v, yt, k4);
        #pragma unroll
        for (int d = 0; d < DD; ++d) {
            v2f s = k1[d] + splat2(2.0f) * (k2[d] + k3[d]) + k4[d];
            y[d] = fma2(splat2(hs * (1.0f / 6.0f)), s, y[d]);
        }
    }

    float wl[DD];
    #pragma unroll
    for (int d = 0; d < DD; ++d) wl[d] = Wl[d];
    v2f o = splat2(bl[0]);
    #pragma unroll
    for (int d = 0; d < DD; ++d) o = fma2(y[d], splat2(wl[d]), o);
    *reinterpret_cast<v2f*>(out + 2 * (size_t)i) = o;
}

extern "C" void kernel_launch(void* const* d_in, const int* in_sizes, int n_in,
                              void* d_out, int out_size, void* d_ws, size_t ws_size,
                              hipStream_t stream) {
    const float* inp = (const float*)d_in[0];
    const float* W1  = (const float*)d_in[1];
    const float* b1  = (const float*)d_in[2];
    const float* W2  = (const float*)d_in[3];
    const float* b2  = (const float*)d_in[4];
    const float* Wl  = (const float*)d_in[5];
    const float* bl  = (const float*)d_in[6];
    float* out = (float*)d_out;
    float* wp  = (float*)d_ws;   // needs HD*WPS*4 = 6.4 KB

    const int B  = in_sizes[0] / (TT * DD);
    const int B2 = B / 2;

    hipLaunchKernelGGL(pack_weights_kernel, dim3(1), dim3(128), 0, stream, W1, b1, W2, wp);

    const int blocks = (B2 + 255) / 256;
    hipLaunchKernelGGL(ODEModel_74732430950754_kernel, dim3(blocks), dim3(256), 0, stream,
                       inp, wp, b2, Wl, bl, out, B2);
}

// Round 3
// 323.749 us; speedup vs baseline: 2.5265x; 1.3799x over previous
//
#include <hip/hip_runtime.h>

#define HD 100   // hidden width
#define DD 6     // state dim
#define TT 8     // timesteps
#define NSTEP 4  // fixed RK4 steps over [0,1]
#define WPS 16   // packed weight row stride (floats) = 64B

// Pack per-h rows: [b1, W1 row (6), W2T row (6), pad(3)] -> 64B rows in ws
__global__ void pack_weights_kernel(const float* __restrict__ W1,
                                    const float* __restrict__ b1,
                                    const float* __restrict__ W2,
                                    float* __restrict__ wp)
{
    int h = blockIdx.x * blockDim.x + threadIdx.x;
    if (h >= HD) return;
    float* row = wp + (size_t)h * WPS;
    row[0] = b1[h];
    #pragma unroll
    for (int d = 0; d < DD; ++d) row[1 + d] = W1[h * DD + d];
    #pragma unroll
    for (int d = 0; d < DD; ++d) row[7 + d] = W2[d * HD + h];
    row[13] = 0.0f; row[14] = 0.0f; row[15] = 0.0f;
}

__device__ __forceinline__ float fast_tanh(float x) {
    // tanh(x) = 1 - 2/(e^{2x}+1); e^{2x} = exp2(x * 2*log2(e))
    float e = __builtin_amdgcn_exp2f(x * 2.885390081777927f);
    return __builtin_fmaf(-2.0f, __builtin_amdgcn_rcpf(e + 1.0f), 1.0f);
}

__device__ __forceinline__ void feval(const float* __restrict__ wp,
                                      const float b2v[DD],
                                      const float (&y)[DD], float (&k)[DD])
{
    #pragma unroll
    for (int d = 0; d < DD; ++d) k[d] = b2v[d];
    #pragma unroll 2
    for (int h = 0; h < HD; ++h) {
        const float* __restrict__ row = wp + (size_t)h * WPS;
        // wave-uniform address -> s_load; scalar float locals -> SGPR operands
        const float wb = row[0];
        const float w0 = row[1], w1 = row[2], w2 = row[3],
                    w3 = row[4], w4 = row[5], w5 = row[6];
        const float u0 = row[7], u1 = row[8], u2 = row[9],
                    u3 = row[10], u4 = row[11], u5 = row[12];
        float pre = wb;
        pre = __builtin_fmaf(y[0], w0, pre);
        pre = __builtin_fmaf(y[1], w1, pre);
        pre = __builtin_fmaf(y[2], w2, pre);
        pre = __builtin_fmaf(y[3], w3, pre);
        pre = __builtin_fmaf(y[4], w4, pre);
        pre = __builtin_fmaf(y[5], w5, pre);
        const float t = fast_tanh(pre);
        k[0] = __builtin_fmaf(t, u0, k[0]);
        k[1] = __builtin_fmaf(t, u1, k[1]);
        k[2] = __builtin_fmaf(t, u2, k[2]);
        k[3] = __builtin_fmaf(t, u3, k[3]);
        k[4] = __builtin_fmaf(t, u4, k[4]);
        k[5] = __builtin_fmaf(t, u5, k[5]);
    }
}

__global__ __launch_bounds__(256) void ODEModel_74732430950754_kernel(
    const float* __restrict__ inp, const float* __restrict__ wp,
    const float* __restrict__ b2, const float* __restrict__ Wl,
    const float* __restrict__ bl, float* __restrict__ out, int B)
{
    const int idx = blockIdx.x * 256 + threadIdx.x;
    if (idx >= B) return;

    float b2v[DD], wl[DD];
    #pragma unroll
    for (int d = 0; d < DD; ++d) { b2v[d] = b2[d]; wl[d] = Wl[d]; }
    const float blv = bl[0];

    // y0 = input_seq[idx, T-1, :]
    float y[DD];
    #pragma unroll
    for (int d = 0; d < DD; ++d)
        y[d] = inp[(size_t)idx * (TT * DD) + (TT - 1) * DD + d];

    const float hs = 1.0f / (float)NSTEP;
    float k1[DD], k2[DD], k3[DD], k4[DD], yt[DD];

    #pragma unroll 1
    for (int st = 0; st < NSTEP; ++st) {
        feval(wp, b2v, y, k1);
        #pragma unroll
        for (int d = 0; d < DD; ++d) yt[d] = __builtin_fmaf(0.5f * hs, k1[d], y[d]);
        feval(wp, b2v, yt, k2);
        #pragma unroll
        for (int d = 0; d < DD; ++d) yt[d] = __builtin_fmaf(0.5f * hs, k2[d], y[d]);
        feval(wp, b2v, yt, k3);
        #pragma unroll
        for (int d = 0; d < DD; ++d) yt[d] = __builtin_fmaf(hs, k3[d], y[d]);
        feval(wp, b2v, yt, k4);
        #pragma unroll
        for (int d = 0; d < DD; ++d) {
            float s = k1[d] + 2.0f * (k2[d] + k3[d]) + k4[d];
            y[d] = __builtin_fmaf(hs * (1.0f / 6.0f), s, y[d]);
        }
    }

    float o = blv;
    #pragma unroll
    for (int d = 0; d < DD; ++d) o = __builtin_fmaf(y[d], wl[d], o);
    out[idx] = o;
}

extern "C" void kernel_launch(void* const* d_in, const int* in_sizes, int n_in,
                              void* d_out, int out_size, void* d_ws, size_t ws_size,
                              hipStream_t stream) {
    const float* inp = (const float*)d_in[0];
    const float* W1  = (const float*)d_in[1];
    const float* b1  = (const float*)d_in[2];
    const float* W2  = (const float*)d_in[3];
    const float* b2  = (const float*)d_in[4];
    const float* Wl  = (const float*)d_in[5];
    const float* bl  = (const float*)d_in[6];
    float* out = (float*)d_out;
    float* wp  = (float*)d_ws;   // needs HD*WPS*4 = 6.4 KB

    const int B = in_sizes[0] / (TT * DD);

    hipLaunchKernelGGL(pack_weights_kernel, dim3(1), dim3(128), 0, stream, W1, b1, W2, wp);

    const int blocks = (B + 255) / 256;
    hipLaunchKernelGGL(ODEModel_74732430950754_kernel, dim3(blocks), dim3(256), 0, stream,
                       inp, wp, b2, Wl, bl, out, B);
}

// Round 4
// 173.692 us; speedup vs baseline: 4.7091x; 1.8639x over previous
//
#include <hip/hip_runtime.h>

#define HD 100    // hidden width
#define HP (HD/2) // hidden pairs
#define DD 6      // state dim
#define TT 8      // timesteps
#define NSTEP 2   // fixed RK4 steps over [0,1]
#define WPS 32    // packed pair-row stride (floats) = 128B

typedef float v2f __attribute__((ext_vector_type(2)));

__device__ __forceinline__ v2f splat2(float s) { v2f r; r.x = s; r.y = s; return r; }
__device__ __forceinline__ v2f fma2(v2f a, v2f b, v2f c) {
    return __builtin_elementwise_fma(a, b, c);
}

// Pack pair rows: [b1(h),b1(h+1) | W1[h][d],W1[h+1][d] d=0..5 | W2[d][h],W2[d][h+1] d=0..5 | pad6]
__global__ void pack_weights_kernel(const float* __restrict__ W1,
                                    const float* __restrict__ b1,
                                    const float* __restrict__ W2,
                                    float* __restrict__ wp)
{
    int p = blockIdx.x * blockDim.x + threadIdx.x;
    if (p >= HP) return;
    const int h = 2 * p;
    float* row = wp + (size_t)p * WPS;
    row[0] = b1[h];
    row[1] = b1[h + 1];
    #pragma unroll
    for (int d = 0; d < DD; ++d) {
        row[2 + 2 * d]  = W1[h * DD + d];
        row[3 + 2 * d]  = W1[(h + 1) * DD + d];
        row[14 + 2 * d] = W2[d * HD + h];
        row[15 + 2 * d] = W2[d * HD + h + 1];
    }
    #pragma unroll
    for (int i = 26; i < WPS; ++i) row[i] = 0.0f;
}

__device__ __forceinline__ v2f tanh2(v2f x) {
    // tanh(x) = 1 - 2/(exp2(2*log2e*x)+1)
    v2f z = x * splat2(2.885390081777927f);
    v2f e;
    e.x = __builtin_amdgcn_exp2f(z.x);
    e.y = __builtin_amdgcn_exp2f(z.y);
    v2f ep = e + splat2(1.0f);
    v2f r;
    r.x = __builtin_amdgcn_rcpf(ep.x);
    r.y = __builtin_amdgcn_rcpf(ep.y);
    return fma2(splat2(-2.0f), r, splat2(1.0f));
}

__device__ __forceinline__ void feval(const float* __restrict__ wp,
                                      const float b2v[DD],
                                      const float (&y)[DD], float (&k)[DD])
{
    v2f kk[DD];
    #pragma unroll
    for (int d = 0; d < DD; ++d) { kk[d].x = b2v[d]; kk[d].y = 0.0f; }
    v2f yy[DD];
    #pragma unroll
    for (int d = 0; d < DD; ++d) yy[d] = splat2(y[d]);

    #pragma unroll 2
    for (int p = 0; p < HP; ++p) {
        // wave-uniform 128B row; v2f elements -> 64-bit SGPR-pair operands
        const v2f* __restrict__ rp = reinterpret_cast<const v2f*>(wp + (size_t)p * WPS);
        v2f pre = rp[0];
        #pragma unroll
        for (int d = 0; d < DD; ++d) pre = fma2(yy[d], rp[1 + d], pre);
        v2f t = tanh2(pre);
        #pragma unroll
        for (int d = 0; d < DD; ++d) kk[d] = fma2(t, rp[7 + d], kk[d]);
    }
    #pragma unroll
    for (int d = 0; d < DD; ++d) k[d] = kk[d].x + kk[d].y;
}

__global__ __launch_bounds__(256) void ODEModel_74732430950754_kernel(
    const float* __restrict__ inp, const float* __restrict__ wp,
    const float* __restrict__ b2, const float* __restrict__ Wl,
    const float* __restrict__ bl, float* __restrict__ out, int B)
{
    const int idx = blockIdx.x * 256 + threadIdx.x;
    if (idx >= B) return;

    float b2v[DD], wl[DD];
    #pragma unroll
    for (int d = 0; d < DD; ++d) { b2v[d] = b2[d]; wl[d] = Wl[d]; }
    const float blv = bl[0];

    float y[DD];
    #pragma unroll
    for (int d = 0; d < DD; ++d)
        y[d] = inp[(size_t)idx * (TT * DD) + (TT - 1) * DD + d];

    const float hs = 1.0f / (float)NSTEP;
    float k1[DD], k2[DD], k3[DD], k4[DD], yt[DD];

    #pragma unroll 1
    for (int st = 0; st < NSTEP; ++st) {
        feval(wp, b2v, y, k1);
        #pragma unroll
        for (int d = 0; d < DD; ++d) yt[d] = __builtin_fmaf(0.5f * hs, k1[d], y[d]);
        feval(wp, b2v, yt, k2);
        #pragma unroll
        for (int d = 0; d < DD; ++d) yt[d] = __builtin_fmaf(0.5f * hs, k2[d], y[d]);
        feval(wp, b2v, yt, k3);
        #pragma unroll
        for (int d = 0; d < DD; ++d) yt[d] = __builtin_fmaf(hs, k3[d], y[d]);
        feval(wp, b2v, yt, k4);
        #pragma unroll
        for (int d = 0; d < DD; ++d) {
            float s = k1[d] + 2.0f * (k2[d] + k3[d]) + k4[d];
            y[d] = __builtin_fmaf(hs * (1.0f / 6.0f), s, y[d]);
        }
    }

    float o = blv;
    #pragma unroll
    for (int d = 0; d < DD; ++d) o = __builtin_fmaf(y[d], wl[d], o);
    out[idx] = o;
}

extern "C" void kernel_launch(void* const* d_in, const int* in_sizes, int n_in,
                              void* d_out, int out_size, void* d_ws, size_t ws_size,
                              hipStream_t stream) {
    const float* inp = (const float*)d_in[0];
    const float* W1  = (const float*)d_in[1];
    const float* b1  = (const float*)d_in[2];
    const float* W2  = (const float*)d_in[3];
    const float* b2  = (const float*)d_in[4];
    const float* Wl  = (const float*)d_in[5];
    const float* bl  = (const float*)d_in[6];
    float* out = (float*)d_out;
    float* wp  = (float*)d_ws;   // needs HP*WPS*4 = 6.4 KB

    const int B = in_sizes[0] / (TT * DD);

    hipLaunchKernelGGL(pack_weights_kernel, dim3(1), dim3(64), 0, stream, W1, b1, W2, wp);

    const int blocks = (B + 255) / 256;
    hipLaunchKernelGGL(ODEModel_74732430950754_kernel, dim3(blocks), dim3(256), 0, stream,
                       inp, wp, b2, Wl, bl, out, B);
}